// Round 1
// baseline (9588.152 us; speedup 1.0000x reference)
//
#include <hip/hip_runtime.h>
#include <math.h>

typedef __attribute__((ext_vector_type(8))) short short8;
typedef __attribute__((ext_vector_type(4))) float floatx4;
typedef unsigned short ushort_t;
typedef unsigned int uint_t;

// Problem constants
constexpr int C_B   = 512;
constexpr int C_T   = 365;
constexpr int C_IN  = 10;
constexpr int C_H   = 256;
constexpr int C_OUT = 20;

// Step grid: 64 L0 blocks (16 mt x 4 ng) + 128 L1 blocks (16 mt x 8 ng).
// Each block owns 32 batch rows; strips (mt) are fully independent.
constexpr int L0B = 64;
constexpr int L1B = 128;
constexpr int NB  = L0B + L1B;   // 192 blocks <= 256 CUs -> all co-resident

// Workspace layout (ushort units for weight planes):
// B planes: mat(3: Whh0,Wih1,Whh1) x plane(hi,lo) x [48 nt][8 ks][64 lane][8]
constexpr size_t PLANE_U = 48ull * 8 * 64 * 8;   // 196608 ushorts
constexpr size_t US_H    = 6 * PLANE_U;          // ushort offset of packed-h region
// h planes: packed uint32 (hi<<16 | lo), plane idx = which(0=h0,1=h1)*2 + parity
constexpr size_t HP_SZU  = 512ull * 256;         // uints per h plane
constexpr unsigned STRIP = 12;                   // blocks per batch strip (4 L0 + 8 L1)
constexpr unsigned SPIN_MAX = 1u << 22;          // deadlock valve (fail visibly, no hang)

__device__ __forceinline__ float fsig(float v)  { return 1.0f / (1.0f + __expf(-v)); }
__device__ __forceinline__ float ftanh(float v) { return 2.0f / (1.0f + __expf(-2.0f * v)) - 1.0f; }

__device__ __forceinline__ void split1(float x, ushort_t& hi, ushort_t& lo) {
    unsigned u = __float_as_uint(x);
    hi = (ushort_t)(u >> 16);
    float r = x - __uint_as_float(u & 0xffff0000u);
    lo = (ushort_t)(__float_as_uint(r) >> 16);
}

// packed h element: top 16 bits = bf16(hi), low 16 bits = bf16(residual)
__device__ __forceinline__ uint_t packsplit(float x) {
    unsigned u = __float_as_uint(x);
    unsigned hib = u & 0xffff0000u;
    float r = x - __uint_as_float(hib);
    return hib | (__float_as_uint(r) >> 16);
}

// Device-scope (sc1) stores/loads: write-through / read-through the coherence
// point so cross-XCD consumers see fresh data without any cache invalidates.
__device__ __forceinline__ void store_h(uint_t* plane, int idx, float v) {
    __hip_atomic_store(plane + idx, packsplit(v), __ATOMIC_RELAXED, __HIP_MEMORY_SCOPE_AGENT);
}
__device__ __forceinline__ float load_h(const uint_t* plane, int idx) {
    uint_t u = __hip_atomic_load((uint_t*)(plane + idx), __ATOMIC_RELAXED, __HIP_MEMORY_SCOPE_AGENT);
    return __uint_as_float(u & 0xffff0000u) + __uint_as_float(u << 16);
}

// Pack one 16-j slice of one gate of one matrix into B-fragment-linear hi/lo planes.
__global__ __launch_bounds__(256) void prep_pack(const float* __restrict__ Whh0,
                                                 const float* __restrict__ Wih1,
                                                 const float* __restrict__ Whh1,
                                                 ushort_t* __restrict__ PW) {
    const int blk = blockIdx.x;            // 144 = mat(3) x g(3) x jb(16)
    const int tid = threadIdx.x;

    // zero the per-strip sync counters (runs before the persistent kernel, stream-ordered)
    if (blk == 0 && tid < 16) {
        uint_t* cnt = (uint_t*)(PW + US_H) + 4 * HP_SZU;
        __hip_atomic_store(cnt + tid, 0u, __ATOMIC_RELAXED, __HIP_MEMORY_SCOPE_AGENT);
    }

    const int mat = blk / 48;
    const int rem = blk % 48;
    const int g   = rem / 16;
    const int jb  = rem % 16;
    const float* S = (mat == 0) ? Whh0 : (mat == 1) ? Wih1 : Whh1;

    const int jl  = tid >> 4;
    const int kc  = tid & 15;
    const int j   = jb * 16 + jl;
    const int nt  = jb * 3 + g;

    const float* src = S + (g * 256 + j) * 256 + kc * 16;
    float f[16];
#pragma unroll
    for (int q = 0; q < 4; q++) {
        float4 v = *(const float4*)(src + q * 4);
        f[q*4+0] = v.x; f[q*4+1] = v.y; f[q*4+2] = v.z; f[q*4+3] = v.w;
    }
    ushort_t hi[16], lo[16];
#pragma unroll
    for (int e = 0; e < 16; e++) split1(f[e], hi[e], lo[e]);

    ushort_t* dhi = PW + (size_t)(mat * 2 + 0) * PLANE_U;
    ushort_t* dlo = PW + (size_t)(mat * 2 + 1) * PLANE_U;
    const int ks = kc >> 1;
#pragma unroll
    for (int hh = 0; hh < 2; hh++) {
        const int quad = (kc & 1) * 2 + hh;
        const int L    = quad * 16 + jl;
        const size_t base = ((size_t)(nt * 8 + ks)) * 512 + L * 8;
        short8 vh, vl;
#pragma unroll
        for (int e = 0; e < 8; e++) { vh[e] = (short)hi[hh*8+e]; vl[e] = (short)lo[hh*8+e]; }
        *(short8*)(dhi + base) = vh;
        *(short8*)(dlo + base) = vl;
    }
}

// Stage one [32][256]-uint packed h tile into hi/lo LDS planes [32][264] ushort.
// Device-scope 8B loads bypass (possibly stale) L1/L2; de-interleave in VALU.
__device__ __forceinline__ void stage_packed(const uint_t* __restrict__ g,
                                             ushort_t* s_hi, ushort_t* s_lo, int tid) {
    const int c0 = (tid & 63) * 4;   // k0 (4 uints = 16B per row-chunk)
    const int r0 = tid >> 6;         // 0..3
#pragma unroll
    for (int rr = 0; rr < 8; rr++) {
        const int row = r0 + rr * 4;
        const uint_t* p = g + row * 256 + c0;
        unsigned long long q0 = __hip_atomic_load((unsigned long long*)(p),
                                __ATOMIC_RELAXED, __HIP_MEMORY_SCOPE_AGENT);
        unsigned long long q1 = __hip_atomic_load((unsigned long long*)(p + 2),
                                __ATOMIC_RELAXED, __HIP_MEMORY_SCOPE_AGENT);
        const uint_t u0 = (uint_t)q0, u1 = (uint_t)(q0 >> 32);
        const uint_t u2 = (uint_t)q1, u3 = (uint_t)(q1 >> 32);
        uint2 hv, lv;
        hv.x = (u0 >> 16) | (u1 & 0xffff0000u);
        hv.y = (u2 >> 16) | (u3 & 0xffff0000u);
        lv.x = (u0 & 0xffffu) | (u1 << 16);
        lv.y = (u2 & 0xffffu) | (u3 << 16);
        *(uint2*)(s_hi + row * 264 + c0) = hv;
        *(uint2*)(s_lo + row * 264 + c0) = lv;
    }
}

// 3 N-tiles x full K=256, 3-pass split-bf16, two M-tiles sharing B regs.
__device__ __forceinline__ void wave_gemm(const ushort_t* sh_hi, const ushort_t* sh_lo,
                                          const ushort_t* __restrict__ bh_base,
                                          const ushort_t* __restrict__ bl_base,
                                          int jbg, int lane, floatx4 acc[3][2]) {
    const int m = lane & 15, quad = lane >> 4;
    const int aoff = m * 264 + quad * 8;
#pragma unroll
    for (int ks = 0; ks < 8; ks++) {
        short8 a0h = *(const short8*)(sh_hi + aoff + ks * 32);
        short8 a0l = *(const short8*)(sh_lo + aoff + ks * 32);
        short8 a1h = *(const short8*)(sh_hi + aoff + 16 * 264 + ks * 32);
        short8 a1l = *(const short8*)(sh_lo + aoff + 16 * 264 + ks * 32);
#pragma unroll
        for (int g = 0; g < 3; g++) {
            const size_t boff = (size_t)(jbg * 3 + g) * 4096 + (size_t)ks * 512 + lane * 8;
            short8 bh = *(const short8*)(bh_base + boff);
            short8 bl = *(const short8*)(bl_base + boff);
            acc[g][0] = __builtin_amdgcn_mfma_f32_16x16x32_bf16(a0h, bh, acc[g][0], 0, 0, 0);
            acc[g][0] = __builtin_amdgcn_mfma_f32_16x16x32_bf16(a0l, bh, acc[g][0], 0, 0, 0);
            acc[g][0] = __builtin_amdgcn_mfma_f32_16x16x32_bf16(a0h, bl, acc[g][0], 0, 0, 0);
            acc[g][1] = __builtin_amdgcn_mfma_f32_16x16x32_bf16(a1h, bh, acc[g][1], 0, 0, 0);
            acc[g][1] = __builtin_amdgcn_mfma_f32_16x16x32_bf16(a1l, bh, acc[g][1], 0, 0, 0);
            acc[g][1] = __builtin_amdgcn_mfma_f32_16x16x32_bf16(a1h, bl, acc[g][1], 0, 0, 0);
        }
    }
}

// Persistent kernel: whole T-loop in one dispatch. Per-strip (12-block) flag
// barrier replaces 366 kernel launches. Strips never interact.
__global__ __launch_bounds__(256) void gru_persistent(
    const float* __restrict__ x,
    const float* __restrict__ Wih0,
    const float* __restrict__ bih0, const float* __restrict__ bhh0,
    const float* __restrict__ bih1, const float* __restrict__ bhh1,
    ushort_t* __restrict__ WS)
{
    __shared__ __align__(16) ushort_t shA_hi[32 * 264], shA_lo[32 * 264];
    __shared__ __align__(16) ushort_t shB_hi[32 * 264], shB_lo[32 * 264];
    __shared__ float xs[32][C_IN];
    __shared__ float ldH[2][3][32][17];

    const int tid  = threadIdx.x;
    const int lane = tid & 63;
    const int w    = tid >> 6;
    const int jlo  = lane & 15;
    const int quad = lane >> 4;
    const bool isL0 = (blockIdx.x < (unsigned)L0B);

    uint_t* const hU  = (uint_t*)(WS + US_H);
    uint_t* const cnt = hU + 4 * HP_SZU;

    int mt, ng;
    if (isL0) { mt = blockIdx.x >> 2; ng = blockIdx.x & 3; }
    else      { const int b2 = blockIdx.x - L0B; mt = b2 >> 3; ng = b2 & 7; }
    const int b0 = mt * 32;
    uint_t* const cme = cnt + mt;

    const int jbg0  = ng * 4 + w;        // L0 wave's jbg
    const int mat   = w >> 1;            // L1: 0 = Wih1 x h0, 1 = Whh1 x h1
    const int jbsub = w & 1;
    const int jbg1  = ng * 2 + jbsub;

    // ---- loop-invariant hoists ----
    float wxr[C_IN], wxz[C_IN], wxn[C_IN];
    float b_r = 0.f, b_z = 0.f, b_in = 0.f, b_hn = 0.f;
    if (isL0) {
        const int j = jbg0 * 16 + jlo;
#pragma unroll
        for (int i = 0; i < C_IN; i++) {
            wxr[i] = Wih0[j * C_IN + i];
            wxz[i] = Wih0[(256 + j) * C_IN + i];
            wxn[i] = Wih0[(512 + j) * C_IN + i];
        }
        b_r  = bih0[j] + bhh0[j];
        b_z  = bih0[256 + j] + bhh0[256 + j];
        b_in = bih0[512 + j];
        b_hn = bhh0[512 + j];
    } else if (mat == 0) {
        const int j = jbg1 * 16 + jlo;
        b_r  = bih1[j] + bhh1[j];
        b_z  = bih1[256 + j] + bhh1[256 + j];
        b_in = bih1[512 + j];
        b_hn = bhh1[512 + j];
    }
    // x-tile index hoists (32x10 floats, elements tid and tid+256)
    const int rA = tid / C_IN, cA = tid - rA * C_IN;
    const int uB = tid + 256;
    const int rB = uB / C_IN, cB = uB - rB * C_IN;
    const int xoffA = (b0 + rA) * (C_T * C_IN) + cA;
    const int xoffB = (b0 + rB) * (C_T * C_IN) + cB;

#pragma unroll 1
    for (int k = 0; k <= C_T; ++k) {
        const int srcp = (k + 1) & 1, dstp = k & 1;
        const bool do_l0 = isL0 && (k < C_T);
        const bool l0z   = (k == 0);
        const bool do_l1 = (!isL0) && (k >= 1);
        const bool l1z   = (k == 1);

        // prefetch x for this step (independent of h) so it hides under the wait
        float xa = 0.f, xb = 0.f;
        if (do_l0) {
            xa = x[xoffA + k * C_IN];
            if (tid < 64) xb = x[xoffB + k * C_IN];
        }

        if (k > 0) {
            if (tid == 0) {
                const uint_t tgt = STRIP * (uint_t)k;
                uint_t it = 0;
                while (__hip_atomic_load(cme, __ATOMIC_RELAXED, __HIP_MEMORY_SCOPE_AGENT) < tgt) {
                    if (++it > SPIN_MAX) break;   // valve: fail visibly instead of hanging
                }
            }
            __syncthreads();
        }

        if (isL0) {
            if (do_l0) {
                xs[rA][cA] = xa;
                if (tid < 64) xs[rB][cB] = xb;
                const uint_t* h0sb = hU + (size_t)srcp * HP_SZU + b0 * 256;
                if (!l0z) stage_packed(h0sb, shA_hi, shA_lo, tid);
                __syncthreads();

                floatx4 acc[3][2];
#pragma unroll
                for (int g = 0; g < 3; g++) { acc[g][0] = (floatx4){0,0,0,0}; acc[g][1] = (floatx4){0,0,0,0}; }
                if (!l0z)
                    wave_gemm(shA_hi, shA_lo, WS, WS + PLANE_U, jbg0, lane, acc);

                const uint_t* h0sf = hU + (size_t)srcp * HP_SZU;
                uint_t* const h0d  = hU + (size_t)dstp * HP_SZU;
                const int j = jbg0 * 16 + jlo;
#pragma unroll
                for (int m = 0; m < 2; m++) {
#pragma unroll
                    for (int r = 0; r < 4; r++) {
                        const int row = m * 16 + quad * 4 + r;
                        float xrv = 0.f, xzv = 0.f, xnv = 0.f;
#pragma unroll
                        for (int i = 0; i < C_IN; i++) {
                            const float xv = xs[row][i];
                            xrv += xv * wxr[i]; xzv += xv * wxz[i]; xnv += xv * wxn[i];
                        }
                        const int gi = (b0 + row) * C_H + j;
                        const float hp = l0z ? 0.f : load_h(h0sf, gi);
                        const float ar  = acc[0][m][r] + xrv + b_r;
                        const float az  = acc[1][m][r] + xzv + b_z;
                        const float inn = xnv + b_in;
                        const float hn  = acc[2][m][r] + b_hn;
                        const float rg = fsig(ar), zg = fsig(az);
                        const float nn = ftanh(inn + rg * hn);
                        store_h(h0d, gi, zg * (hp - nn) + nn);
                    }
                }
            }
        } else {
            if (do_l1) {
                const uint_t* h0sb = hU + (size_t)srcp * HP_SZU + b0 * 256;
                const uint_t* h1sb = hU + (size_t)(2 + srcp) * HP_SZU + b0 * 256;
                stage_packed(h0sb, shA_hi, shA_lo, tid);
                if (!l1z) stage_packed(h1sb, shB_hi, shB_lo, tid);
                __syncthreads();

                floatx4 acc[3][2];
#pragma unroll
                for (int g = 0; g < 3; g++) { acc[g][0] = (floatx4){0,0,0,0}; acc[g][1] = (floatx4){0,0,0,0}; }
                if (mat == 0)
                    wave_gemm(shA_hi, shA_lo, WS + 2 * PLANE_U, WS + 3 * PLANE_U, jbg1, lane, acc);
                else if (!l1z)
                    wave_gemm(shB_hi, shB_lo, WS + 4 * PLANE_U, WS + 5 * PLANE_U, jbg1, lane, acc);

                if (mat == 1) {
#pragma unroll
                    for (int g = 0; g < 3; g++)
#pragma unroll
                        for (int m = 0; m < 2; m++)
#pragma unroll
                            for (int r = 0; r < 4; r++)
                                ldH[jbsub][g][m * 16 + quad * 4 + r][jlo] = acc[g][m][r];
                }
                __syncthreads();

                if (mat == 0) {
                    const int j = jbg1 * 16 + jlo;
                    const uint_t* h1sf = hU + (size_t)(2 + srcp) * HP_SZU;
                    uint_t* const h1d  = hU + (size_t)(2 + dstp) * HP_SZU;
#pragma unroll
                    for (int m = 0; m < 2; m++) {
#pragma unroll
                        for (int r = 0; r < 4; r++) {
                            const int row = m * 16 + quad * 4 + r;
                            const int gi = (b0 + row) * C_H + j;
                            const float hp = l1z ? 0.f : load_h(h1sf, gi);
                            const float ar  = acc[0][m][r] + ldH[jbsub][0][row][jlo] + b_r;
                            const float az  = acc[1][m][r] + ldH[jbsub][1][row][jlo] + b_z;
                            const float inn = acc[2][m][r] + b_in;
                            const float hn  = ldH[jbsub][2][row][jlo] + b_hn;
                            const float rg = fsig(ar), zg = fsig(az);
                            const float nn = ftanh(inn + rg * hn);
                            store_h(h1d, gi, zg * (hp - nn) + nn);
                        }
                    }
                }
            }
        }

        // publish this step: barrier drains vmcnt for all waves, then RELEASE add
        // (waitcnt + wbl2 on a clean L2 is cheap; flag lands after all sc1 h stores)
        __syncthreads();
        if (tid == 0)
            __hip_atomic_fetch_add(cme, 1u, __ATOMIC_RELEASE, __HIP_MEMORY_SCOPE_AGENT);
    }
}

__global__ __launch_bounds__(256) void classifier_kernel(
    const ushort_t* __restrict__ WS,
    const float* __restrict__ Wout, const float* __restrict__ bout,
    float* __restrict__ out)
{
    __shared__ float hs[32][C_H + 4];
    __shared__ float lg[32 * C_OUT];
    const int tid = threadIdx.x;
    const int b0  = blockIdx.x * 32;
    // final h1 written at k=365 -> parity 1 -> plane index 2+1 = 3
    const uint_t* hp1 = (const uint_t*)(WS + US_H) + 3 * HP_SZU;
#pragma unroll
    for (int i = 0; i < 32; i++) hs[i][tid] = load_h(hp1, (b0 + i) * C_H + tid);
    __syncthreads();
    for (int u = tid; u < 32 * C_OUT; u += 256) {
        int bb = u / C_OUT, o = u - bb * C_OUT;
        const float* wr = Wout + o * C_H;
        float acc = bout[o];
#pragma unroll 4
        for (int k = 0; k < C_H; k += 4) {
            float4 wv = *(const float4*)(wr + k);
            float4 hv = *(const float4*)(&hs[bb][k]);
            acc += wv.x*hv.x + wv.y*hv.y + wv.z*hv.z + wv.w*hv.w;
        }
        lg[u] = acc;
    }
    __syncthreads();
    if (tid < 32) {
        float mx = -1e30f;
#pragma unroll
        for (int o = 0; o < C_OUT; o++) mx = fmaxf(mx, lg[tid * C_OUT + o]);
        float e[C_OUT];
        float s = 0.0f;
#pragma unroll
        for (int o = 0; o < C_OUT; o++) { e[o] = __expf(lg[tid * C_OUT + o] - mx); s += e[o]; }
        float inv = 1.0f / s;
#pragma unroll
        for (int o = 0; o < C_OUT; o++) out[(b0 + tid) * C_OUT + o] = e[o] * inv;
    }
}

extern "C" void kernel_launch(void* const* d_in, const int* in_sizes, int n_in,
                              void* d_out, int out_size, void* d_ws, size_t ws_size,
                              hipStream_t stream) {
    const float* x    = (const float*)d_in[0];
    // d_in[1] = times (unused), d_in[2] = interpolation_method (unused)
    const float* Wih0 = (const float*)d_in[3];
    const float* Whh0 = (const float*)d_in[4];
    const float* bih0 = (const float*)d_in[5];
    const float* bhh0 = (const float*)d_in[6];
    const float* Wih1 = (const float*)d_in[7];
    const float* Whh1 = (const float*)d_in[8];
    const float* bih1 = (const float*)d_in[9];
    const float* bhh1 = (const float*)d_in[10];
    const float* Wout = (const float*)d_in[11];
    const float* bout = (const float*)d_in[12];
    float* out = (float*)d_out;
    ushort_t* WS = (ushort_t*)d_ws;

    // pack weights + zero per-strip counters
    prep_pack<<<144, 256, 0, stream>>>(Whh0, Wih1, Whh1, WS);
    // whole recurrence in ONE dispatch (replaces 366 launches)
    gru_persistent<<<NB, 256, 0, stream>>>(x, Wih0, bih0, bhh0, bih1, bhh1, WS);
    classifier_kernel<<<C_B / 32, 256, 0, stream>>>(WS, Wout, bout, out);
}